// Round 13
// baseline (1905.134 us; speedup 1.0000x reference)
//
#include <hip/hip_runtime.h>
#include <math.h>

namespace {

typedef __attribute__((ext_vector_type(8))) short short8;
typedef __attribute__((ext_vector_type(4))) float f32x4;
typedef __attribute__((ext_vector_type(2))) float f2v;

__device__ inline unsigned short f2bf(float x) {
    unsigned u = __float_as_uint(x);
    unsigned r = (u + 0x7FFF + ((u >> 16) & 1)) >> 16;
    return (unsigned short)r;
}

__device__ inline f2v nt2(const f2v* p) { return __builtin_nontemporal_load(p); }
__device__ inline long long ntll(const long long* p) { return __builtin_nontemporal_load(p); }

// full-wave (64-lane) sum via DPP on the VALU pipe — no LDS-pipe traffic.
__device__ inline float wave_sum64(float x) {
    int t;
    t = __builtin_amdgcn_update_dpp(0, __float_as_int(x), 0x111, 0xf, 0xf, true);
    x += __int_as_float(t);
    t = __builtin_amdgcn_update_dpp(0, __float_as_int(x), 0x112, 0xf, 0xf, true);
    x += __int_as_float(t);
    t = __builtin_amdgcn_update_dpp(0, __float_as_int(x), 0x114, 0xf, 0xf, true);
    x += __int_as_float(t);
    t = __builtin_amdgcn_update_dpp(0, __float_as_int(x), 0x118, 0xf, 0xf, true);
    x += __int_as_float(t);
    t = __builtin_amdgcn_update_dpp(0, __float_as_int(x), 0x142, 0xa, 0xf, true);
    x += __int_as_float(t);
    t = __builtin_amdgcn_update_dpp(0, __float_as_int(x), 0x143, 0xc, 0xf, true);
    x += __int_as_float(t);
    return __int_as_float(__builtin_amdgcn_readlane(__float_as_int(x), 63));
}

// fused prologue: edge-dtype detect + w3 + weight pack (grid 128 x 256)
__global__ void kprep(const int* __restrict__ edge, const float* __restrict__ a,
                      const float* __restrict__ a2, int* __restrict__ flag,
                      unsigned short* __restrict__ Bp12, unsigned short* __restrict__ Bp3,
                      float* __restrict__ w3) {
    int tid = blockIdx.x * blockDim.x + threadIdx.x;
    if (tid < 32768) {
        int j = tid & 7, l = (tid >> 3) & 63, s = (tid >> 9) & 3, f = tid >> 11;
        int col = f * 16 + (l & 15);
        int k = s * 32 + ((l >> 4) << 3) + j;
        float v = (col < 128) ? a[col * 384 + k] : a[(col - 128) * 384 + 128 + k];
        Bp12[tid] = f2bf(v);
    }
    if (tid < 16384) {
        int j = tid & 7, l = (tid >> 3) & 63, s = (tid >> 9) & 3, f = tid >> 11;
        int col = f * 16 + (l & 15);
        int k = s * 32 + ((l >> 4) << 3) + j;
        Bp3[tid] = f2bf(a[col * 384 + 256 + k]);
    }
    if (blockIdx.x == 0 && threadIdx.x < 64) {
        int hw = edge[2 * threadIdx.x + 1];
        unsigned long long b = __ballot(hw == 0);
        if (threadIdx.x == 0) *flag = (b == ~0ull) ? 1 : 0;
    }
    if (blockIdx.x == 1 && threadIdx.x < 128) {
        int k = threadIdx.x;
        float s = 0.f;
        for (int j = 0; j < 128; ++j) s += a2[j] * a[j * 384 + 256 + k];
        w3[k] = s;
    }
}

// Fused: blocks [0, nb1) do the U/Vb MFMA GEMM (x reps for measurement);
// blocks [nb1, nb1+1024) count edges (once — atomics).
__global__ __launch_bounds__(256) void kA(const float* __restrict__ input,
                                          const unsigned short* __restrict__ Bp,
                                          const float* __restrict__ a2,
                                          float* __restrict__ U,
                                          unsigned short* __restrict__ Vb,
                                          float* __restrict__ su, float* __restrict__ sv,
                                          const int* __restrict__ edge,
                                          const int* __restrict__ flag,
                                          int* __restrict__ counts,
                                          int n, int E, int nb1, int reps) {
    __shared__ char Asb[16384];  // 64 rows x 128 bf16, XOR-swizzled
    if (blockIdx.x >= nb1) {
        bool is64 = (*flag != 0);
        int half = E >> 1;
        int stride = 1024 * 256;
        for (int i = (blockIdx.x - nb1) * 256 + threadIdx.x; i < half; i += stride) {
            int s0, s1;
            if (is64) { int4 v = ((const int4*)edge)[i]; s0 = v.x; s1 = v.z; }
            else      { int2 v = ((const int2*)edge)[i]; s0 = v.x; s1 = v.y; }
            atomicAdd(&counts[s0], 1);
            atomicAdd(&counts[s1], 1);
        }
        if ((E & 1) && blockIdx.x == nb1 && threadIdx.x == 0) {
            int i = E - 1;
            int s = is64 ? edge[2 * (size_t)i] : edge[i];
            atomicAdd(&counts[s], 1);
        }
        return;
    }
    // ---- GEMM body (idempotent; repeated for measurement) ----
    for (int rep = 0; rep < reps; ++rep) {
        int tid = threadIdx.x;
        int wid = tid >> 6, lane = tid & 63;
        int rb = blockIdx.x * 64;
        const float4* inp4 = (const float4*)input;
        for (int it = tid; it < 2048; it += 256) {
            int row = it >> 5, c4 = it & 31;
            int gr = rb + row;
            float4 v = make_float4(0.f, 0.f, 0.f, 0.f);
            if (gr < n) v = inp4[(size_t)gr * 32 + c4];
            unsigned long long pk = (unsigned long long)f2bf(v.x) |
                                    ((unsigned long long)f2bf(v.y) << 16) |
                                    ((unsigned long long)f2bf(v.z) << 32) |
                                    ((unsigned long long)f2bf(v.w) << 48);
            int byte = (row * 256 + c4 * 8) ^ ((row & 7) << 4);
            *(unsigned long long*)(Asb + byte) = pk;
        }
        __syncthreads();

        f32x4 acc[16];
        #pragma unroll
        for (int f = 0; f < 16; ++f) acc[f] = (f32x4){0.f, 0.f, 0.f, 0.f};
        const short8* Bf = (const short8*)Bp;
        int arow = (wid << 4) | (lane & 15);
        int abase = arow * 256 + ((lane >> 4) << 4);
        int xorv = (arow & 7) << 4;
        #pragma unroll
        for (int s = 0; s < 4; ++s) {
            short8 af = *(const short8*)(Asb + ((abase + s * 64) ^ xorv));
            #pragma unroll
            for (int f = 0; f < 16; ++f)
                acc[f] = __builtin_amdgcn_mfma_f32_16x16x32_bf16(af, Bf[(f * 4 + s) * 64 + lane],
                                                                 acc[f], 0, 0, 0);
        }

        int rloc = (wid << 4) + ((lane >> 4) << 2);
        int cb = lane & 15;
        #pragma unroll
        for (int f = 0; f < 16; ++f) {
            int col = f * 16 + cb;
            #pragma unroll
            for (int reg = 0; reg < 4; ++reg) {
                int r = rb + rloc + reg;
                if (r < n) {
                    if (col < 128) U[(size_t)r * 128 + col] = acc[f][reg];
                    else           Vb[(size_t)r * 128 + (col - 128)] = f2bf(acc[f][reg]);
                }
            }
        }

        float coef[8];
        #pragma unroll
        for (int f = 0; f < 8; ++f) coef[f] = a2[f * 16 + cb];
        #pragma unroll
        for (int reg = 0; reg < 4; ++reg) {
            float pu = 0.f, pv = 0.f;
            #pragma unroll
            for (int f = 0; f < 8; ++f) {
                pu += acc[f][reg] * coef[f];
                pv += acc[f + 8][reg] * coef[f];
            }
            #pragma unroll
            for (int off = 1; off < 16; off <<= 1) {
                pu += __shfl_xor(pu, off);
                pv += __shfl_xor(pv, off);
            }
            int r = rb + rloc + reg;
            if (cb == 0 && r < n) { su[r] = pu; sv[r] = pv; }
        }
        __syncthreads();
    }
}

// k3a: per-chunk (1024) exclusive scan; zeroes counts for reuse as cursor.
__global__ __launch_bounds__(1024) void k3a(int* __restrict__ counts,
                                            int* __restrict__ row_start,
                                            int* __restrict__ partials, int n) {
    __shared__ int wsum[16];
    int tid = threadIdx.x;
    int i = blockIdx.x * 1024 + tid;
    int lane = tid & 63, wv = tid >> 6;
    int v = 0;
    if (i < n) { v = counts[i]; counts[i] = 0; }
    int x = v;
    #pragma unroll
    for (int off = 1; off < 64; off <<= 1) {
        int t = __shfl_up(x, off);
        if (lane >= off) x += t;
    }
    if (lane == 63) wsum[wv] = x;
    __syncthreads();
    if (wv == 0) {
        int ws = (lane < 16) ? wsum[lane] : 0;
        #pragma unroll
        for (int off = 1; off < 16; off <<= 1) {
            int t = __shfl_up(ws, off);
            if (lane >= off) ws += t;
        }
        if (lane < 16) wsum[lane] = ws;
    }
    __syncthreads();
    int woff = (wv > 0) ? wsum[wv - 1] : 0;
    if (i < n) row_start[i] = woff + x - v;   // chunk-local exclusive
    if (tid == 1023) partials[blockIdx.x] = wsum[15];
}

// k3b: scan chunk partials -> poffs; row_start[n] = total.
__global__ void k3b(const int* __restrict__ partials, int* __restrict__ poffs,
                    int* __restrict__ row_start, int nb, int n) {
    int lane = threadIdx.x;  // 64 threads
    int carry = 0;
    for (int base = 0; base < nb; base += 64) {
        int v = (base + lane < nb) ? partials[base + lane] : 0;
        int x = v;
        #pragma unroll
        for (int off = 1; off < 64; off <<= 1) {
            int t = __shfl_up(x, off);
            if (lane >= off) x += t;
        }
        if (base + lane < nb) poffs[base + lane] = carry + x - v;
        carry += __shfl(x, 63);
    }
    if (lane == 0) row_start[n] = carry;
}

// scatter: pos = row_start[s] + poffs[s>>10] + counts[s]++   (counts zeroed by k3a)
__global__ void k4_scatter(const int* __restrict__ edge, const int* __restrict__ flag,
                           const int* __restrict__ row_start, const int* __restrict__ poffs,
                           int* __restrict__ counts, long long* __restrict__ epack, int E) {
    bool is64 = (*flag != 0);
    int half = E >> 1;
    int stride = gridDim.x * blockDim.x;
    const int* dbase = edge + (is64 ? 2 * (size_t)E : (size_t)E);
    for (int i = blockIdx.x * blockDim.x + threadIdx.x; i < half; i += stride) {
        int s0, s1, d0, d1;
        if (is64) {
            int4 v = ((const int4*)edge)[i];  s0 = v.x; s1 = v.z;
            int4 w = ((const int4*)dbase)[i]; d0 = w.x; d1 = w.z;
        } else {
            int2 v = ((const int2*)edge)[i];  s0 = v.x; s1 = v.y;
            int2 w = ((const int2*)dbase)[i]; d0 = w.x; d1 = w.y;
        }
        int p0 = row_start[s0] + poffs[s0 >> 10] + atomicAdd(&counts[s0], 1);
        epack[p0] = (long long)(unsigned)(2 * i) | ((long long)(unsigned)d0 << 32);
        int p1 = row_start[s1] + poffs[s1 >> 10] + atomicAdd(&counts[s1], 1);
        epack[p1] = (long long)(unsigned)(2 * i + 1) | ((long long)(unsigned)d1 << 32);
    }
    if ((E & 1) && blockIdx.x == 0 && threadIdx.x == 0) {
        int i = E - 1;
        int s = is64 ? edge[2 * (size_t)i] : edge[i];
        int d = is64 ? dbase[2 * (size_t)i] : dbase[i];
        int pos = row_start[s] + poffs[s >> 10] + atomicAdd(&counts[s], 1);
        epack[pos] = (long long)(unsigned)i | ((long long)(unsigned)d << 32);
    }
}

// one wave per node; 8-edge batches, DPP reduction; reps for measurement.
__global__ __launch_bounds__(256, 3) void k5_agg(const float* __restrict__ edge_embed,
                                                 const unsigned short* __restrict__ Vb,
                                                 const float* __restrict__ su,
                                                 const float* __restrict__ sv,
                                                 const float* __restrict__ w3,
                                                 const int* __restrict__ row_start,
                                                 const int* __restrict__ poffs,
                                                 const long long* __restrict__ epack,
                                                 float* __restrict__ T, float* __restrict__ W,
                                                 float* __restrict__ rowsum, int n, int reps) {
    int w = (int)(((size_t)blockIdx.x * blockDim.x + threadIdx.x) >> 6);
    int lane = threadIdx.x & 63;
    if (w >= n) return;
    int start = row_start[w] + poffs[w >> 10];
    int end = (w + 1 < n) ? (row_start[w + 1] + poffs[(w + 1) >> 10]) : row_start[n];
    f2v w3v = ((const f2v*)w3)[lane];
    float su_n = su[w];
    const f2v* EE = (const f2v*)edge_embed;
    const unsigned* VV = (const unsigned*)Vb;  // bf16x2 per lane
    for (int rep = 0; rep < reps; ++rep) {
        f2v Tacc = 0.f, Wacc = 0.f;
        float rs = 0.f;
        long long eds[8];
        #pragma unroll
        for (int i = 0; i < 8; ++i)
            eds[i] = (start + i < end) ? ntll(&epack[start + i]) : 0;
        for (int e0 = start; e0 < end; e0 += 8) {
            int nb = end - e0;
            if (nb > 8) nb = 8;
            long long edsn[8];
            #pragma unroll
            for (int i = 0; i < 8; ++i) {
                int idx = e0 + 8 + i;
                edsn[i] = (idx < end) ? ntll(&epack[idx]) : 0;
            }
            f2v emb[8], vv[8];
            float svv[8], part[8];
            #pragma unroll
            for (int i = 0; i < 8; ++i) {
                if (i < nb) {
                    int eid = (int)eds[i];
                    int dst = (int)(eds[i] >> 32);
                    emb[i] = nt2(EE + (size_t)eid * 64 + lane);
                    unsigned pv = VV[(size_t)dst * 64 + lane];
                    vv[i].x = __uint_as_float(pv << 16);
                    vv[i].y = __uint_as_float(pv & 0xffff0000u);
                    svv[i] = sv[dst];
                } else {
                    emb[i] = 0.f; vv[i] = 0.f; svv[i] = 0.f;
                }
            }
            #pragma unroll
            for (int i = 0; i < 8; ++i)
                part[i] = wave_sum64(emb[i].x * w3v.x + emb[i].y * w3v.y);
            #pragma unroll
            for (int i = 0; i < 8; ++i) {
                if (i < nb) {
                    float s = su_n + svv[i] + part[i];
                    float lr = (s > 0.f) ? s : 0.2f * s;
                    float ee = __expf(-lr);
                    rs += ee;
                    Tacc += ee * emb[i];
                    Wacc += ee * vv[i];
                }
            }
            #pragma unroll
            for (int i = 0; i < 8; ++i) eds[i] = edsn[i];
        }
        ((f2v*)T)[(size_t)w * 64 + lane] = Tacc;
        ((f2v*)W)[(size_t)w * 64 + lane] = Wacc;
        if (lane == 0) rowsum[w] = rs;
    }
}

// out = elu(U + (T @ a3^T + W) / rowsum); MFMA + LDS-bounce epilogue; reps for measurement.
__global__ __launch_bounds__(256) void k6_mfma(const float* __restrict__ T,
                                               const unsigned short* __restrict__ Bp3,
                                               const float* __restrict__ U,
                                               const float* __restrict__ W,
                                               const float* __restrict__ rowsum,
                                               float* __restrict__ out, int n, int reps) {
    __shared__ char Lds[64 * 132 * 4];
    int tid = threadIdx.x;
    int wid = tid >> 6, lane = tid & 63;
    int rb = blockIdx.x * 64;
    for (int rep = 0; rep < reps; ++rep) {
        const float4* t4 = (const float4*)T;
        for (int it = tid; it < 2048; it += 256) {
            int row = it >> 5, c4 = it & 31;
            int gr = rb + row;
            float4 v = make_float4(0.f, 0.f, 0.f, 0.f);
            if (gr < n) v = t4[(size_t)gr * 32 + c4];
            unsigned long long pk = (unsigned long long)f2bf(v.x) |
                                    ((unsigned long long)f2bf(v.y) << 16) |
                                    ((unsigned long long)f2bf(v.z) << 32) |
                                    ((unsigned long long)f2bf(v.w) << 48);
            int byte = (row * 256 + c4 * 8) ^ ((row & 7) << 4);
            *(unsigned long long*)(Lds + byte) = pk;
        }
        __syncthreads();

        f32x4 acc[8];
        #pragma unroll
        for (int f = 0; f < 8; ++f) acc[f] = (f32x4){0.f, 0.f, 0.f, 0.f};
        const short8* Bf = (const short8*)Bp3;
        int arow = (wid << 4) | (lane & 15);
        int abase = arow * 256 + ((lane >> 4) << 4);
        int xorv = (arow & 7) << 4;
        #pragma unroll
        for (int s = 0; s < 4; ++s) {
            short8 af = *(const short8*)(Lds + ((abase + s * 64) ^ xorv));
            #pragma unroll
            for (int f = 0; f < 8; ++f)
                acc[f] = __builtin_amdgcn_mfma_f32_16x16x32_bf16(af, Bf[(f * 4 + s) * 64 + lane],
                                                                 acc[f], 0, 0, 0);
        }
        __syncthreads();

        float* Fs = (float*)Lds;
        int rloc = (wid << 4) + ((lane >> 4) << 2);
        int cb = lane & 15;
        #pragma unroll
        for (int f = 0; f < 8; ++f) {
            #pragma unroll
            for (int reg = 0; reg < 4; ++reg)
                Fs[(rloc + reg) * 132 + f * 16 + cb] = acc[f][reg];
        }
        __syncthreads();

        #pragma unroll
        for (int i = 0; i < 8; ++i) {
            int flat = tid + i * 256;
            int row = flat >> 5, c4 = flat & 31;
            int r = rb + row;
            if (r < n) {
                f32x4 t = *(const f32x4*)&Fs[row * 132 + c4 * 4];
                float rs = rowsum[r];
                f32x4 o;
                if (rs > 0.f) {
                    f32x4 u = *(const f32x4*)&U[(size_t)r * 128 + c4 * 4];
                    f32x4 w = *(const f32x4*)&W[(size_t)r * 128 + c4 * 4];
                    float inv = 1.f / rs;
                    float hx = u.x + (t.x + w.x) * inv;
                    float hy = u.y + (t.y + w.y) * inv;
                    float hz = u.z + (t.z + w.z) * inv;
                    float hw = u.w + (t.w + w.w) * inv;
                    o.x = (hx > 0.f) ? hx : expm1f(hx);
                    o.y = (hy > 0.f) ? hy : expm1f(hy);
                    o.z = (hz > 0.f) ? hz : expm1f(hz);
                    o.w = (hw > 0.f) ? hw : expm1f(hw);
                } else {
                    o = (f32x4){0.f, 0.f, 0.f, 0.f};
                }
                __builtin_nontemporal_store(o, (f32x4*)&out[(size_t)r * 128 + c4 * 4]);
            }
        }
        __syncthreads();
    }
}

}  // namespace

extern "C" void kernel_launch(void* const* d_in, const int* in_sizes, int n_in,
                              void* d_out, int out_size, void* d_ws, size_t ws_size,
                              hipStream_t stream) {
    const float* input      = (const float*)d_in[0];
    const float* edge_embed = (const float*)d_in[1];
    const float* a          = (const float*)d_in[2];
    const float* a2         = (const float*)d_in[3];
    const int*   edge       = (const int*)d_in[4];
    float* out = (float*)d_out;

    const int n = in_sizes[0] / 128;   // 50000
    const int E = in_sizes[1] / 128;   // 1000000

    char* p = (char*)d_ws;
    auto carve = [&](size_t bytes) -> char* {
        char* q = p;
        p += (bytes + 255) & ~(size_t)255;
        return q;
    };
    float* U         = (float*)carve((size_t)n * 128 * 4);
    unsigned short* Vb = (unsigned short*)carve((size_t)n * 128 * 2);
    float* T         = (float*)carve((size_t)n * 128 * 4);
    float* W         = (float*)carve((size_t)n * 128 * 4);
    float* su        = (float*)carve((size_t)n * 4);
    float* sv        = (float*)carve((size_t)n * 4);
    float* rowsum    = (float*)carve((size_t)n * 4);
    float* w3        = (float*)carve(128 * 4);
    int*   counts    = (int*)carve((size_t)n * 4);
    int*   row_start = (int*)carve((size_t)(n + 1) * 4);
    long long* epack = (long long*)carve((size_t)E * 8);
    unsigned short* Bp12 = (unsigned short*)carve(32768 * 2);
    unsigned short* Bp3  = (unsigned short*)carve(16384 * 2);
    int*   partials  = (int*)carve(4096 * 4);
    int*   poffs     = (int*)carve(4096 * 4);
    int*   flag      = (int*)carve(4);

    const int NB = (n + 1023) / 1024;
    const int nb1 = (n + 63) / 64;

    hipMemsetAsync(counts, 0, (size_t)n * 4, stream);

    // MEASUREMENT ROUND 2: kA x10, k5 x6, k6 x12 — all three clear the ~300 µs
    // fill cutoff and appear in top-5 with counters; k4 = total residual.
    kprep<<<128, 256, 0, stream>>>(edge, a, a2, flag, Bp12, Bp3, w3);
    kA<<<nb1 + 1024, 256, 0, stream>>>(input, Bp12, a2, U, Vb, su, sv,
                                       edge, flag, counts, n, E, nb1, /*reps=*/10);
    k3a<<<NB, 1024, 0, stream>>>(counts, row_start, partials, n);
    k3b<<<1, 64, 0, stream>>>(partials, poffs, row_start, NB, n);
    k4_scatter<<<1024, 256, 0, stream>>>(edge, flag, row_start, poffs, counts, epack, E);
    k5_agg<<<(n + 3) / 4, 256, 0, stream>>>(edge_embed, Vb, su, sv, w3,
                                            row_start, poffs, epack, T, W, rowsum, n,
                                            /*reps=*/6);
    k6_mfma<<<(n + 63) / 64, 256, 0, stream>>>(T, Bp3, U, W, rowsum, out, n, /*reps=*/12);
}

// Round 14
// 305.558 us; speedup vs baseline: 6.2349x; 6.2349x over previous
//
#include <hip/hip_runtime.h>
#include <math.h>

namespace {

typedef __attribute__((ext_vector_type(8))) short short8;
typedef __attribute__((ext_vector_type(4))) float f32x4;
typedef __attribute__((ext_vector_type(4))) unsigned u32x4;
typedef __attribute__((ext_vector_type(2))) float f2v;

__device__ inline unsigned short f2bf(float x) {
    unsigned u = __float_as_uint(x);
    unsigned r = (u + 0x7FFF + ((u >> 16) & 1)) >> 16;
    return (unsigned short)r;
}

__device__ inline f32x4 nt4(const f32x4* p) { return __builtin_nontemporal_load(p); }
__device__ inline float bfl(unsigned u) { return __uint_as_float(u << 16); }
__device__ inline float bfh(unsigned u) { return __uint_as_float(u & 0xffff0000u); }

// all-lanes sum within each 16-lane row via DPP row_ror 8/4/2/1 (VALU pipe only)
__device__ inline float row_allsum16(float x) {
    int t;
    t = __builtin_amdgcn_update_dpp(0, __float_as_int(x), 0x128, 0xf, 0xf, true);
    x += __int_as_float(t);
    t = __builtin_amdgcn_update_dpp(0, __float_as_int(x), 0x124, 0xf, 0xf, true);
    x += __int_as_float(t);
    t = __builtin_amdgcn_update_dpp(0, __float_as_int(x), 0x122, 0xf, 0xf, true);
    x += __int_as_float(t);
    t = __builtin_amdgcn_update_dpp(0, __float_as_int(x), 0x121, 0xf, 0xf, true);
    x += __int_as_float(t);
    return x;
}

// fused prologue: edge-dtype detect + w3 + weight pack (grid 128 x 256)
__global__ void kprep(const int* __restrict__ edge, const float* __restrict__ a,
                      const float* __restrict__ a2, int* __restrict__ flag,
                      unsigned short* __restrict__ Bp12, unsigned short* __restrict__ Bp3,
                      float* __restrict__ w3) {
    int tid = blockIdx.x * blockDim.x + threadIdx.x;
    if (tid < 32768) {
        int j = tid & 7, l = (tid >> 3) & 63, s = (tid >> 9) & 3, f = tid >> 11;
        int col = f * 16 + (l & 15);
        int k = s * 32 + ((l >> 4) << 3) + j;
        float v = (col < 128) ? a[col * 384 + k] : a[(col - 128) * 384 + 128 + k];
        Bp12[tid] = f2bf(v);
    }
    if (tid < 16384) {
        int j = tid & 7, l = (tid >> 3) & 63, s = (tid >> 9) & 3, f = tid >> 11;
        int col = f * 16 + (l & 15);
        int k = s * 32 + ((l >> 4) << 3) + j;
        Bp3[tid] = f2bf(a[col * 384 + 256 + k]);
    }
    if (blockIdx.x == 0 && threadIdx.x < 64) {
        int hw = edge[2 * threadIdx.x + 1];
        unsigned long long b = __ballot(hw == 0);
        if (threadIdx.x == 0) *flag = (b == ~0ull) ? 1 : 0;
    }
    if (blockIdx.x == 1 && threadIdx.x < 128) {
        int k = threadIdx.x;
        float s = 0.f;
        for (int j = 0; j < 128; ++j) s += a2[j] * a[j * 384 + 256 + k];
        w3[k] = s;
    }
}

// Fused: blocks [0, nb1) do the U/Vb MFMA GEMM; blocks [nb1, nb1+1024) count edges.
__global__ __launch_bounds__(256) void kA(const float* __restrict__ input,
                                          const unsigned short* __restrict__ Bp,
                                          const float* __restrict__ a2,
                                          float* __restrict__ U,
                                          unsigned short* __restrict__ Vb,
                                          float* __restrict__ su, float* __restrict__ sv,
                                          const int* __restrict__ edge,
                                          const int* __restrict__ flag,
                                          int* __restrict__ counts,
                                          int n, int E, int nb1) {
    __shared__ char Asb[16384];  // 64 rows x 128 bf16, XOR-swizzled
    if (blockIdx.x >= nb1) {
        bool is64 = (*flag != 0);
        int half = E >> 1;
        int stride = 1024 * 256;
        for (int i = (blockIdx.x - nb1) * 256 + threadIdx.x; i < half; i += stride) {
            int s0, s1;
            if (is64) { int4 v = ((const int4*)edge)[i]; s0 = v.x; s1 = v.z; }
            else      { int2 v = ((const int2*)edge)[i]; s0 = v.x; s1 = v.y; }
            atomicAdd(&counts[s0], 1);
            atomicAdd(&counts[s1], 1);
        }
        if ((E & 1) && blockIdx.x == nb1 && threadIdx.x == 0) {
            int i = E - 1;
            int s = is64 ? edge[2 * (size_t)i] : edge[i];
            atomicAdd(&counts[s], 1);
        }
        return;
    }
    // ---- GEMM body ----
    int tid = threadIdx.x;
    int wid = tid >> 6, lane = tid & 63;
    int rb = blockIdx.x * 64;
    const float4* inp4 = (const float4*)input;
    for (int it = tid; it < 2048; it += 256) {
        int row = it >> 5, c4 = it & 31;
        int gr = rb + row;
        float4 v = make_float4(0.f, 0.f, 0.f, 0.f);
        if (gr < n) v = inp4[(size_t)gr * 32 + c4];
        unsigned long long pk = (unsigned long long)f2bf(v.x) |
                                ((unsigned long long)f2bf(v.y) << 16) |
                                ((unsigned long long)f2bf(v.z) << 32) |
                                ((unsigned long long)f2bf(v.w) << 48);
        int byte = (row * 256 + c4 * 8) ^ ((row & 7) << 4);
        *(unsigned long long*)(Asb + byte) = pk;
    }
    __syncthreads();

    f32x4 acc[16];
    #pragma unroll
    for (int f = 0; f < 16; ++f) acc[f] = (f32x4){0.f, 0.f, 0.f, 0.f};
    const short8* Bf = (const short8*)Bp;
    int arow = (wid << 4) | (lane & 15);
    int abase = arow * 256 + ((lane >> 4) << 4);
    int xorv = (arow & 7) << 4;
    #pragma unroll
    for (int s = 0; s < 4; ++s) {
        short8 af = *(const short8*)(Asb + ((abase + s * 64) ^ xorv));
        #pragma unroll
        for (int f = 0; f < 16; ++f)
            acc[f] = __builtin_amdgcn_mfma_f32_16x16x32_bf16(af, Bf[(f * 4 + s) * 64 + lane],
                                                             acc[f], 0, 0, 0);
    }

    int rloc = (wid << 4) + ((lane >> 4) << 2);
    int cb = lane & 15;
    #pragma unroll
    for (int f = 0; f < 16; ++f) {
        int col = f * 16 + cb;
        #pragma unroll
        for (int reg = 0; reg < 4; ++reg) {
            int r = rb + rloc + reg;
            if (r < n) {
                if (col < 128) U[(size_t)r * 128 + col] = acc[f][reg];
                else           Vb[(size_t)r * 128 + (col - 128)] = f2bf(acc[f][reg]);
            }
        }
    }

    float coef[8];
    #pragma unroll
    for (int f = 0; f < 8; ++f) coef[f] = a2[f * 16 + cb];
    #pragma unroll
    for (int reg = 0; reg < 4; ++reg) {
        float pu = 0.f, pv = 0.f;
        #pragma unroll
        for (int f = 0; f < 8; ++f) {
            pu += acc[f][reg] * coef[f];
            pv += acc[f + 8][reg] * coef[f];
        }
        #pragma unroll
        for (int off = 1; off < 16; off <<= 1) {
            pu += __shfl_xor(pu, off);
            pv += __shfl_xor(pv, off);
        }
        int r = rb + rloc + reg;
        if (cb == 0 && r < n) { su[r] = pu; sv[r] = pv; }
    }
}

// k3a: per-chunk (1024) exclusive scan; zeroes counts for reuse as cursor.
__global__ __launch_bounds__(1024) void k3a(int* __restrict__ counts,
                                            int* __restrict__ row_start,
                                            int* __restrict__ partials, int n) {
    __shared__ int wsum[16];
    int tid = threadIdx.x;
    int i = blockIdx.x * 1024 + tid;
    int lane = tid & 63, wv = tid >> 6;
    int v = 0;
    if (i < n) { v = counts[i]; counts[i] = 0; }
    int x = v;
    #pragma unroll
    for (int off = 1; off < 64; off <<= 1) {
        int t = __shfl_up(x, off);
        if (lane >= off) x += t;
    }
    if (lane == 63) wsum[wv] = x;
    __syncthreads();
    if (wv == 0) {
        int ws = (lane < 16) ? wsum[lane] : 0;
        #pragma unroll
        for (int off = 1; off < 16; off <<= 1) {
            int t = __shfl_up(ws, off);
            if (lane >= off) ws += t;
        }
        if (lane < 16) wsum[lane] = ws;
    }
    __syncthreads();
    int woff = (wv > 0) ? wsum[wv - 1] : 0;
    if (i < n) row_start[i] = woff + x - v;   // chunk-local exclusive
    if (tid == 1023) partials[blockIdx.x] = wsum[15];
}

// k3b: scan chunk partials -> poffs; row_start[n] = total.
__global__ void k3b(const int* __restrict__ partials, int* __restrict__ poffs,
                    int* __restrict__ row_start, int nb, int n) {
    int lane = threadIdx.x;  // 64 threads
    int carry = 0;
    for (int base = 0; base < nb; base += 64) {
        int v = (base + lane < nb) ? partials[base + lane] : 0;
        int x = v;
        #pragma unroll
        for (int off = 1; off < 64; off <<= 1) {
            int t = __shfl_up(x, off);
            if (lane >= off) x += t;
        }
        if (base + lane < nb) poffs[base + lane] = carry + x - v;
        carry += __shfl(x, 63);
    }
    if (lane == 0) row_start[n] = carry;
}

// scatter: pos = row_start[s] + poffs[s>>10] + counts[s]++   (counts zeroed by k3a)
__global__ void k4_scatter(const int* __restrict__ edge, const int* __restrict__ flag,
                           const int* __restrict__ row_start, const int* __restrict__ poffs,
                           int* __restrict__ counts, long long* __restrict__ epack, int E) {
    bool is64 = (*flag != 0);
    int half = E >> 1;
    int stride = gridDim.x * blockDim.x;
    const int* dbase = edge + (is64 ? 2 * (size_t)E : (size_t)E);
    for (int i = blockIdx.x * blockDim.x + threadIdx.x; i < half; i += stride) {
        int s0, s1, d0, d1;
        if (is64) {
            int4 v = ((const int4*)edge)[i];  s0 = v.x; s1 = v.z;
            int4 w = ((const int4*)dbase)[i]; d0 = w.x; d1 = w.z;
        } else {
            int2 v = ((const int2*)edge)[i];  s0 = v.x; s1 = v.y;
            int2 w = ((const int2*)dbase)[i]; d0 = w.x; d1 = w.y;
        }
        int p0 = row_start[s0] + poffs[s0 >> 10] + atomicAdd(&counts[s0], 1);
        epack[p0] = (long long)(unsigned)(2 * i) | ((long long)(unsigned)d0 << 32);
        int p1 = row_start[s1] + poffs[s1 >> 10] + atomicAdd(&counts[s1], 1);
        epack[p1] = (long long)(unsigned)(2 * i + 1) | ((long long)(unsigned)d1 << 32);
    }
    if ((E & 1) && blockIdx.x == 0 && threadIdx.x == 0) {
        int i = E - 1;
        int s = is64 ? edge[2 * (size_t)i] : edge[i];
        int d = is64 ? dbase[2 * (size_t)i] : dbase[i];
        int pos = row_start[s] + poffs[s >> 10] + atomicAdd(&counts[s], 1);
        epack[pos] = (long long)(unsigned)i | ((long long)(unsigned)d << 32);
    }
}

// k5 v2: one wave per node; 16 LANES PER EDGE (4 edges per wave-instruction).
// lane = g*16+j: handles floats j*8..j*8+7 of edge (e0+g). Per 8 edges:
// 2 epack broadcasts + 4 emb float4-loads + 2 V dwordx4 + 2 sv — vs 25 loads before.
// Score reduce: DPP row_ror allreduce within 16 lanes (8 VALU ops per 4 edges).
// Cross-group combine via shfl_xor(16/32) once per NODE.
__global__ __launch_bounds__(256) void k5_agg(const float* __restrict__ edge_embed,
                                              const unsigned short* __restrict__ Vb,
                                              const float* __restrict__ su,
                                              const float* __restrict__ sv,
                                              const float* __restrict__ w3,
                                              const int* __restrict__ row_start,
                                              const int* __restrict__ poffs,
                                              const long long* __restrict__ epack,
                                              float* __restrict__ T, float* __restrict__ W,
                                              float* __restrict__ rowsum, int n) {
    int w = (int)(((size_t)blockIdx.x * blockDim.x + threadIdx.x) >> 6);
    int lane = threadIdx.x & 63;
    if (w >= n) return;
    int g = lane >> 4, j = lane & 15;
    int start = row_start[w] + poffs[w >> 10];
    int end = (w + 1 < n) ? (row_start[w + 1] + poffs[(w + 1) >> 10]) : row_start[n];
    const f32x4* EE4 = (const f32x4*)edge_embed;          // 32 f32x4 per row
    f32x4 w3a = ((const f32x4*)w3)[j * 2];
    f32x4 w3b = ((const f32x4*)w3)[j * 2 + 1];
    float su_n = su[w];
    f32x4 Ta = 0.f, Tb = 0.f, Wa = 0.f, Wb = 0.f;
    float rs = 0.f;
    for (int e0 = start; e0 < end; e0 += 8) {
        int ia = e0 + g, ib = e0 + 4 + g;
        bool va = ia < end, vb = ib < end;
        long long eda = va ? epack[ia] : 0;               // 16-lane broadcast, L2-hot
        long long edb = vb ? epack[ib] : 0;
        int eida = (int)eda, dsta = (int)(eda >> 32);
        int eidb = (int)edb, dstb = (int)(edb >> 32);
        f32x4 ea0 = nt4(EE4 + (size_t)eida * 32 + j * 2);
        f32x4 ea1 = nt4(EE4 + (size_t)eida * 32 + j * 2 + 1);
        f32x4 eb0 = nt4(EE4 + (size_t)eidb * 32 + j * 2);
        f32x4 eb1 = nt4(EE4 + (size_t)eidb * 32 + j * 2 + 1);
        u32x4 vua = *(const u32x4*)(Vb + (size_t)dsta * 128 + j * 8);
        u32x4 vub = *(const u32x4*)(Vb + (size_t)dstb * 128 + j * 8);
        float sva = sv[dsta], svb = sv[dstb];
        float pa = ea0.x * w3a.x + ea0.y * w3a.y + ea0.z * w3a.z + ea0.w * w3a.w +
                   ea1.x * w3b.x + ea1.y * w3b.y + ea1.z * w3b.z + ea1.w * w3b.w;
        float pb = eb0.x * w3a.x + eb0.y * w3a.y + eb0.z * w3a.z + eb0.w * w3a.w +
                   eb1.x * w3b.x + eb1.y * w3b.y + eb1.z * w3b.z + eb1.w * w3b.w;
        pa = row_allsum16(pa);
        pb = row_allsum16(pb);
        float sa = su_n + sva + pa;
        float sb = su_n + svb + pb;
        float la = (sa > 0.f) ? sa : 0.2f * sa;
        float lb = (sb > 0.f) ? sb : 0.2f * sb;
        float eea = va ? __expf(-la) : 0.f;
        float eeb = vb ? __expf(-lb) : 0.f;
        rs += eea + eeb;
        Ta += eea * ea0; Tb += eea * ea1;
        Ta += eeb * eb0; Tb += eeb * eb1;
        f32x4 vfa0 = {bfl(vua.x), bfh(vua.x), bfl(vua.y), bfh(vua.y)};
        f32x4 vfa1 = {bfl(vua.z), bfh(vua.z), bfl(vua.w), bfh(vua.w)};
        f32x4 vfb0 = {bfl(vub.x), bfh(vub.x), bfl(vub.y), bfh(vub.y)};
        f32x4 vfb1 = {bfl(vub.z), bfh(vub.z), bfl(vub.w), bfh(vub.w)};
        Wa += eea * vfa0; Wb += eea * vfa1;
        Wa += eeb * vfb0; Wb += eeb * vfb1;
    }
    // combine the 4 groups (lane strides 16/32), once per node
    #pragma unroll
    for (int k = 0; k < 4; ++k) {
        Ta[k] += __shfl_xor(Ta[k], 16); Ta[k] += __shfl_xor(Ta[k], 32);
        Tb[k] += __shfl_xor(Tb[k], 16); Tb[k] += __shfl_xor(Tb[k], 32);
        Wa[k] += __shfl_xor(Wa[k], 16); Wa[k] += __shfl_xor(Wa[k], 32);
        Wb[k] += __shfl_xor(Wb[k], 16); Wb[k] += __shfl_xor(Wb[k], 32);
    }
    rs += __shfl_xor(rs, 16); rs += __shfl_xor(rs, 32);
    if (g == 0) {
        ((f32x4*)T)[(size_t)w * 32 + j * 2] = Ta;
        ((f32x4*)T)[(size_t)w * 32 + j * 2 + 1] = Tb;
        ((f32x4*)W)[(size_t)w * 32 + j * 2] = Wa;
        ((f32x4*)W)[(size_t)w * 32 + j * 2 + 1] = Wb;
    }
    if (lane == 0) rowsum[w] = rs;
}

// out = elu(U + (T @ a3^T + W) / rowsum); MFMA + LDS-bounce vectorized epilogue.
__global__ __launch_bounds__(256) void k6_mfma(const float* __restrict__ T,
                                               const unsigned short* __restrict__ Bp3,
                                               const float* __restrict__ U,
                                               const float* __restrict__ W,
                                               const float* __restrict__ rowsum,
                                               float* __restrict__ out, int n) {
    __shared__ char Lds[64 * 132 * 4];  // 33 KB; first 16 KB doubles as bf16 A-staging
    int tid = threadIdx.x;
    int wid = tid >> 6, lane = tid & 63;
    int rb = blockIdx.x * 64;
    const float4* t4 = (const float4*)T;
    for (int it = tid; it < 2048; it += 256) {
        int row = it >> 5, c4 = it & 31;
        int gr = rb + row;
        float4 v = make_float4(0.f, 0.f, 0.f, 0.f);
        if (gr < n) v = t4[(size_t)gr * 32 + c4];
        unsigned long long pk = (unsigned long long)f2bf(v.x) |
                                ((unsigned long long)f2bf(v.y) << 16) |
                                ((unsigned long long)f2bf(v.z) << 32) |
                                ((unsigned long long)f2bf(v.w) << 48);
        int byte = (row * 256 + c4 * 8) ^ ((row & 7) << 4);
        *(unsigned long long*)(Lds + byte) = pk;
    }
    __syncthreads();

    f32x4 acc[8];
    #pragma unroll
    for (int f = 0; f < 8; ++f) acc[f] = (f32x4){0.f, 0.f, 0.f, 0.f};
    const short8* Bf = (const short8*)Bp3;
    int arow = (wid << 4) | (lane & 15);
    int abase = arow * 256 + ((lane >> 4) << 4);
    int xorv = (arow & 7) << 4;
    #pragma unroll
    for (int s = 0; s < 4; ++s) {
        short8 af = *(const short8*)(Lds + ((abase + s * 64) ^ xorv));
        #pragma unroll
        for (int f = 0; f < 8; ++f)
            acc[f] = __builtin_amdgcn_mfma_f32_16x16x32_bf16(af, Bf[(f * 4 + s) * 64 + lane],
                                                             acc[f], 0, 0, 0);
    }
    __syncthreads();  // all ds_reads complete before float overwrite

    float* Fs = (float*)Lds;
    int rloc = (wid << 4) + ((lane >> 4) << 2);
    int cb = lane & 15;
    #pragma unroll
    for (int f = 0; f < 8; ++f) {
        #pragma unroll
        for (int reg = 0; reg < 4; ++reg)
            Fs[(rloc + reg) * 132 + f * 16 + cb] = acc[f][reg];
    }
    __syncthreads();

    #pragma unroll
    for (int i = 0; i < 8; ++i) {
        int flat = tid + i * 256;       // 0..2047
        int row = flat >> 5, c4 = flat & 31;
        int r = rb + row;
        if (r < n) {
            f32x4 t = *(const f32x4*)&Fs[row * 132 + c4 * 4];
            float rs = rowsum[r];
            f32x4 o;
            if (rs > 0.f) {
                f32x4 u = *(const f32x4*)&U[(size_t)r * 128 + c4 * 4];
                f32x4 w = *(const f32x4*)&W[(size_t)r * 128 + c4 * 4];
                float inv = 1.f / rs;
                float hx = u.x + (t.x + w.x) * inv;
                float hy = u.y + (t.y + w.y) * inv;
                float hz = u.z + (t.z + w.z) * inv;
                float hw = u.w + (t.w + w.w) * inv;
                o.x = (hx > 0.f) ? hx : expm1f(hx);
                o.y = (hy > 0.f) ? hy : expm1f(hy);
                o.z = (hz > 0.f) ? hz : expm1f(hz);
                o.w = (hw > 0.f) ? hw : expm1f(hw);
            } else {
                o = (f32x4){0.f, 0.f, 0.f, 0.f};
            }
            __builtin_nontemporal_store(o, (f32x4*)&out[(size_t)r * 128 + c4 * 4]);
        }
    }
}

}  // namespace

extern "C" void kernel_launch(void* const* d_in, const int* in_sizes, int n_in,
                              void* d_out, int out_size, void* d_ws, size_t ws_size,
                              hipStream_t stream) {
    const float* input      = (const float*)d_in[0];
    const float* edge_embed = (const float*)d_in[1];
    const float* a          = (const float*)d_in[2];
    const float* a2         = (const float*)d_in[3];
    const int*   edge       = (const int*)d_in[4];
    float* out = (float*)d_out;

    const int n = in_sizes[0] / 128;   // 50000
    const int E = in_sizes[1] / 128;   // 1000000

    char* p = (char*)d_ws;
    auto carve = [&](size_t bytes) -> char* {
        char* q = p;
        p += (bytes + 255) & ~(size_t)255;
        return q;
    };
    float* U         = (float*)carve((size_t)n * 128 * 4);
    unsigned short* Vb = (unsigned short*)carve((size_t)n * 128 * 2);
    float* T         = (float*)carve((size_t)n * 128 * 4);
    float* W         = (float*)carve((size_t)n * 128 * 4);
    float* su        = (float*)carve((size_t)n * 4);
    float* sv        = (float*)carve((size_t)n * 4);
    float* rowsum    = (float*)carve((size_t)n * 4);
    float* w3        = (float*)carve(128 * 4);
    int*   counts    = (int*)carve((size_t)n * 4);
    int*   row_start = (int*)carve((size_t)(n + 1) * 4);
    long long* epack = (long long*)carve((size_t)E * 8);
    unsigned short* Bp12 = (unsigned short*)carve(32768 * 2);
    unsigned short* Bp3  = (unsigned short*)carve(16384 * 2);
    int*   partials  = (int*)carve(4096 * 4);
    int*   poffs     = (int*)carve(4096 * 4);
    int*   flag      = (int*)carve(4);

    const int NB = (n + 1023) / 1024;
    const int nb1 = (n + 63) / 64;

    hipMemsetAsync(counts, 0, (size_t)n * 4, stream);

    kprep<<<128, 256, 0, stream>>>(edge, a, a2, flag, Bp12, Bp3, w3);
    kA<<<nb1 + 1024, 256, 0, stream>>>(input, Bp12, a2, U, Vb, su, sv,
                                       edge, flag, counts, n, E, nb1);
    k3a<<<NB, 1024, 0, stream>>>(counts, row_start, partials, n);
    k3b<<<1, 64, 0, stream>>>(partials, poffs, row_start, NB, n);
    k4_scatter<<<1024, 256, 0, stream>>>(edge, flag, row_start, poffs, counts, epack, E);
    k5_agg<<<(n + 3) / 4, 256, 0, stream>>>(edge_embed, Vb, su, sv, w3,
                                            row_start, poffs, epack, T, W, rowsum, n);
    k6_mfma<<<(n + 63) / 64, 256, 0, stream>>>(T, Bp3, U, W, rowsum, out, n);
}